// Round 17
// baseline (194.588 us; speedup 1.0000x reference)
//
#include <hip/hip_runtime.h>
#include <hip/hip_bf16.h>
#include <math.h>

#define BB   4
#define CC   32
#define HH   120
#define WW   160
#define NH_  8
#define HD   20
#define HDP  32            // head dim padded to 32; slots 30/31 = softmax bias
#define NN   3840          // sequence length (C*H)
#define ROWS 3840
#define NBH  32            // B * NH
#define LOG2E 1.44269504088896f

typedef float f32x4 __attribute__((ext_vector_type(4)));
typedef short s16x8 __attribute__((ext_vector_type(8)));
typedef short s16x4 __attribute__((ext_vector_type(4)));

static __device__ __forceinline__ unsigned short f2bf(float x) {
    return __builtin_bit_cast(unsigned short, __float2bfloat16(x));
}
static __device__ __forceinline__ float bf2f(unsigned short u) {
    unsigned v = ((unsigned)u) << 16;
    return __builtin_bit_cast(float, v);
}
static __device__ __forceinline__ float exp2fast(float x) {
#if defined(__has_builtin) && __has_builtin(__builtin_amdgcn_exp2f)
    return __builtin_amdgcn_exp2f(x);
#else
    float r; asm("v_exp_f32 %0, %1" : "=v"(r) : "v"(x)); return r;
#endif
}

// exp2 four lanes then pack to bf16 (round-half-up) as an s16x4 B-frag.
// BUILTIN-ONLY pack — validated R5/R9-R16. Do NOT use the cvt_pk inline-asm
// variant (R7/R8 corruption in unrolled loops).
static __device__ __forceinline__ s16x4 exp4_pack(f32x4 e) {
    unsigned u0 = __builtin_bit_cast(unsigned, exp2fast(e[0])) + 0x8000u;
    unsigned u1 = __builtin_bit_cast(unsigned, exp2fast(e[1])) + 0x8000u;
    unsigned u2 = __builtin_bit_cast(unsigned, exp2fast(e[2])) + 0x8000u;
    unsigned u3 = __builtin_bit_cast(unsigned, exp2fast(e[3])) + 0x8000u;
    uint2 w;
#if defined(__has_builtin) && __has_builtin(__builtin_amdgcn_perm)
    w.x = __builtin_amdgcn_perm(u1, u0, 0x07060302u);
    w.y = __builtin_amdgcn_perm(u3, u2, 0x07060302u);
#else
    w.x = (u0 >> 16) | (u1 & 0xffff0000u);
    w.y = (u2 >> 16) | (u3 & 0xffff0000u);
#endif
    return __builtin_bit_cast(s16x4, w);
}

static __device__ __forceinline__ f32x4 mfma32(s16x8 a, s16x8 b, f32x4 c) {
    return __builtin_amdgcn_mfma_f32_16x16x32_bf16(a, b, c, 0, 0, 0);
}
// concat two s16x4 into a K=32 fragment half-pair (register pairing, no ops)
static __device__ __forceinline__ s16x8 cat44(s16x4 a, s16x4 b) {
    s16x8 r;
    r[0]=a[0]; r[1]=a[1]; r[2]=a[2]; r[3]=a[3];
    r[4]=b[0]; r[5]=b[1]; r[6]=b[2]; r[7]=b[3];
    return r;
}

// ---------------- W prep: f32 -> bf16 [o][k]; Wq pre-scaled by log2(e) ----
__global__ __launch_bounds__(256)
void wprep_kernel(const float* __restrict__ Wq, const float* __restrict__ Wk,
                  const float* __restrict__ Wv,
                  unsigned short* __restrict__ wqb, unsigned short* __restrict__ wkb,
                  unsigned short* __restrict__ wvb)
{
    int i = blockIdx.x*256 + threadIdx.x;
    if (i < WW*WW) {
        wqb[i] = f2bf(Wq[i] * LOG2E);
        wkb[i] = f2bf(Wk[i]);
        wvb[i] = f2bf(Wv[i]);
    }
}

// ---------------- ones: kt bias slots 30/31 = bf16(1.0) ------------------
// Enables E' = E + qt[m][30]*1 + qt[m][31]*1 inside the attn E-MFMA.
__global__ __launch_bounds__(256)
void ones_kernel(unsigned short* __restrict__ kt)
{
    int i = blockIdx.x*256 + threadIdx.x;   // over NBH*NN
    if (i < NBH*NN) {
        kt[(size_t)i*HDP + 30] = 0x3F80;    // bf16(1.0)
        kt[(size_t)i*HDP + 31] = 0x3F80;
    }
}

// ---------------- Projection via MFMA (no LDS) ---------------------------
// qt/kt: [bh][n][32] bf16 (d<20 written; pads memset-0; qt slots 30/31 get
// the -log2(Z) bias from zinv later). vt: quad-major RAW v:
// vt[bh][q=m/4][dp][m%4] (dp pads memset-0).
__global__ __launch_bounds__(256)
void proj_mfma_kernel(const float* __restrict__ x,
                      const unsigned short* __restrict__ wqb,
                      const unsigned short* __restrict__ wkb,
                      const unsigned short* __restrict__ wvb,
                      const float* __restrict__ bq, const float* __restrict__ bk,
                      const float* __restrict__ bv,
                      unsigned short* __restrict__ qt, unsigned short* __restrict__ kt,
                      unsigned short* __restrict__ vt)
{
    const int tid  = threadIdx.x;
    const int wv   = tid >> 6;
    const int lane = tid & 63;
    const int g = lane >> 4, c = lane & 15;
    const int r0 = blockIdx.x*64 + wv*16;

    s16x8 A[5];
    const float* xrow = x + (size_t)(r0 + c)*WW;
    #pragma unroll
    for (int s = 0; s < 5; ++s) {
        float4 v0 = *(const float4*)(xrow + s*32 + g*8);
        float4 v1 = *(const float4*)(xrow + s*32 + g*8 + 4);
        s16x8 a;
        a[0]=(short)f2bf(v0.x); a[1]=(short)f2bf(v0.y);
        a[2]=(short)f2bf(v0.z); a[3]=(short)f2bf(v0.w);
        a[4]=(short)f2bf(v1.x); a[5]=(short)f2bf(v1.y);
        a[6]=(short)f2bf(v1.z); a[7]=(short)f2bf(v1.w);
        A[s] = a;
    }

    size_t baseqk[4], vq0[4];
    #pragma unroll
    for (int rr = 0; rr < 4; ++rr) {
        int R  = r0 + g*4 + rr;
        int b  = R / ROWS;
        int r  = R % ROWS;
        int nh = r / 480;
        int rm = r % 480;
        int d  = rm / 24;
        int n1 = rm % 24;
        int bh = b*NH_ + nh;
        baseqk[rr] = ((size_t)bh*NN + n1*160)*HDP + d;
        // quad-major v: off = bh*NN*HDP + (n>>2)*128 + d*4 + (n&3),
        // n = n1*160 + o  ->  (n>>2) = n1*40 + (o>>2), (n&3) = (o&3)
        vq0[rr]    = (size_t)bh*NN*HDP + (size_t)(n1*40)*(HDP*4) + (size_t)d*4;
    }

    const f32x4 zero4 = {0.f, 0.f, 0.f, 0.f};
    for (int nt = 0; nt < 10; ++nt) {
        const size_t wbase = (size_t)(nt*16 + c)*WW;
        f32x4 aq = zero4, ak = zero4, av = zero4;
        #pragma unroll
        for (int s = 0; s < 5; ++s) {
            s16x8 Bq = *(const s16x8*)(wqb + wbase + s*32 + g*8);
            aq = mfma32(A[s], Bq, aq);
            s16x8 Bk = *(const s16x8*)(wkb + wbase + s*32 + g*8);
            ak = mfma32(A[s], Bk, ak);
            s16x8 Bv = *(const s16x8*)(wvb + wbase + s*32 + g*8);
            av = mfma32(A[s], Bv, av);
        }
        const int o = nt*16 + c;
        const float bqv = bq[o]*LOG2E, bkv = bk[o], bvv = bv[o];
        #pragma unroll
        for (int rr = 0; rr < 4; ++rr) {
            qt[baseqk[rr] + (size_t)o*HDP] = f2bf(aq[rr] + bqv);
            kt[baseqk[rr] + (size_t)o*HDP] = f2bf(ak[rr] + bkv);
            vt[vq0[rr] + (size_t)(o >> 2)*(HDP*4) + (o & 3)] = f2bf(av[rr] + bvv);
        }
    }
}

// ---------------- Pass 1: softmax bias lz[m] = -log2(Z[m]) -> qt slots ---
// R12-exact E/exp body. Output changed: instead of zinv[], write the
// two-slot bf16 split of -log2(Z) into qt[m][30..31]. Safe: each block
// reads only its OWN qt rows (before its write) and kt (never written
// here); kt slots 30/31=1.0 contribute qt_slot(=0)*1 = 0 to this E.
__global__ __launch_bounds__(256, 4)
void zinv_kernel(unsigned short* __restrict__ qt,
                 const unsigned short* __restrict__ kt)
{
    __shared__ float zred[4][64];
    const int blk  = ((int)blockIdx.x & 7) * (NBH*(NN/64)/8) + ((int)blockIdx.x >> 3);
    const int bh   = blk / (NN/64);
    const int m0   = (blk % (NN/64)) * 64;
    const int tid  = threadIdx.x;
    const int wv   = tid >> 6;
    const int lane = tid & 63;
    const int g = lane >> 4, c = lane & 15;

    s16x8 qa[4];
    #pragma unroll
    for (int ms = 0; ms < 4; ++ms)
        qa[ms] = *(const s16x8*)(qt + ((size_t)bh*NN + m0 + ms*16 + c)*HDP + g*8);

    const f32x4 zero4 = {0.f, 0.f, 0.f, 0.f};
    f32x4 z[4];
    #pragma unroll
    for (int ms = 0; ms < 4; ++ms) z[ms] = zero4;

    const unsigned short* kbase = kt + (size_t)bh*NN*HDP;
    const int nbeg = wv * (NN/4);
    const int nend = nbeg + NN/4;

    s16x8 kb0 = *(const s16x8*)(kbase + (size_t)(nbeg +      c)*HDP + g*8);
    s16x8 kb1 = *(const s16x8*)(kbase + (size_t)(nbeg + 16 + c)*HDP + g*8);

    for (int n = nbeg; n < nend - 32; n += 32) {
        s16x8 nk0 = *(const s16x8*)(kbase + (size_t)(n + 32 +      c)*HDP + g*8);
        s16x8 nk1 = *(const s16x8*)(kbase + (size_t)(n + 48 +      c)*HDP + g*8);
        #pragma unroll
        for (int ms = 0; ms < 4; ++ms) {
            f32x4 e0 = mfma32(qa[ms], kb0, zero4);
            f32x4 e1 = mfma32(qa[ms], kb1, zero4);
            #pragma unroll
            for (int rr = 0; rr < 4; ++rr)
                z[ms][rr] += exp2fast(e0[rr]) + exp2fast(e1[rr]);
        }
        kb0 = nk0; kb1 = nk1;
    }
    #pragma unroll
    for (int ms = 0; ms < 4; ++ms) {
        f32x4 e0 = mfma32(qa[ms], kb0, zero4);
        f32x4 e1 = mfma32(qa[ms], kb1, zero4);
        #pragma unroll
        for (int rr = 0; rr < 4; ++rr)
            z[ms][rr] += exp2fast(e0[rr]) + exp2fast(e1[rr]);
    }

    #pragma unroll
    for (int ms = 0; ms < 4; ++ms) {
        #pragma unroll
        for (int rr = 0; rr < 4; ++rr) {
            float v = z[ms][rr];
            v += __shfl_xor(v, 1);
            v += __shfl_xor(v, 2);
            v += __shfl_xor(v, 4);
            v += __shfl_xor(v, 8);
            if (c == 0) zred[wv][ms*16 + g*4 + rr] = v;
        }
    }
    __syncthreads();
    if (tid < 64) {
        float s = zred[0][tid] + zred[1][tid] + zred[2][tid] + zred[3][tid];
        float lzf = -__log2f(s);
        unsigned short hi = f2bf(lzf);
        unsigned short lo = f2bf(lzf - bf2f(hi));   // residual: ~1e-4 exp err
        size_t qoff = ((size_t)bh*NN + m0 + tid)*HDP;
        qt[qoff + 30] = hi;
        qt[qoff + 31] = lo;
    }
}

// ---------------- Pass 2: out = V * exp2(E + lz[m]) ----------------------
// R16-exact body (passing, 90.6us). Only change: V pointer is the RAW
// quad-major vt (normalization now rides in E via qt slots 30/31 x kt=1).
__global__ __launch_bounds__(256, 3)
void attn_out_kernel(const unsigned short* __restrict__ qt,
                     const unsigned short* __restrict__ kt,
                     const unsigned short* __restrict__ vt,
                     float* __restrict__ y)
{
    __shared__ float red[3][32][64];   // 24 KB
    const int blk  = ((int)blockIdx.x & 7) * (NBH*(NN/64)/8) + ((int)blockIdx.x >> 3);
    const int bh   = blk / (NN/64);
    const int n0   = (blk % (NN/64)) * 64;
    const int tid  = threadIdx.x;
    const int wv   = tid >> 6;
    const int lane = tid & 63;
    const int g = lane >> 4, c = lane & 15;
    const int b = bh >> 3, nh = bh & 7;

    const f32x4 zero4 = {0.f, 0.f, 0.f, 0.f};
    const unsigned short* qb  = qt + (size_t)bh*NN*HDP;
    const unsigned short* kbp = kt + (size_t)bh*NN*HDP;
    const unsigned short* vp  = vt + (size_t)bh*HDP*NN;

    s16x8 kb[4];
    #pragma unroll
    for (int ns = 0; ns < 4; ++ns)
        kb[ns] = *(const s16x8*)(kbp + ((size_t)(n0 + ns*16 + c))*HDP + g*8);

    f32x4 acc[2][4];
    #pragma unroll
    for (int ds = 0; ds < 2; ++ds)
        #pragma unroll
        for (int ns = 0; ns < 4; ++ns) acc[ds][ns] = zero4;

    const int mbeg = wv * (NN/4);          // 960 m per wave = 15 steps of 64
    const int mend = mbeg + NN/4;

    // va[ds][j] = V[ds*16+c][m + j*16 + g*4 ..+3] from quad-major vt
    s16x8 qa[4];
    s16x4 va[2][4];
    #pragma unroll
    for (int j = 0; j < 4; ++j)
        qa[j] = *(const s16x8*)(qb + ((size_t)(mbeg + j*16 + c))*HDP + g*8);
    #pragma unroll
    for (int ds = 0; ds < 2; ++ds)
        #pragma unroll
        for (int j = 0; j < 4; ++j)
            va[ds][j] = *(const s16x4*)(vp + (size_t)((mbeg >> 2) + j*4 + g)*(HDP*4)
                                           + (ds*16 + c)*4);

    for (int m0 = mbeg; m0 < mend - 64; m0 += 64) {
        const int m1 = m0 + 64;
        // prefetch next step
        s16x8 nqa[4];
        s16x4 nva[2][4];
        #pragma unroll
        for (int j = 0; j < 4; ++j)
            nqa[j] = *(const s16x8*)(qb + ((size_t)(m1 + j*16 + c))*HDP + g*8);
        #pragma unroll
        for (int ds = 0; ds < 2; ++ds)
            #pragma unroll
            for (int j = 0; j < 4; ++j)
                nva[ds][j] = *(const s16x4*)(vp + (size_t)((m1 >> 2) + j*4 + g)*(HDP*4)
                                                + (ds*16 + c)*4);

        #pragma unroll
        for (int ns = 0; ns < 4; ++ns) {
            f32x4 e0 = mfma32(qa[0], kb[ns], zero4);
            f32x4 e1 = mfma32(qa[1], kb[ns], zero4);
            f32x4 e2 = mfma32(qa[2], kb[ns], zero4);
            f32x4 e3 = mfma32(qa[3], kb[ns], zero4);
            s16x8 P01 = cat44(exp4_pack(e0), exp4_pack(e1));   // pi order
            s16x8 P23 = cat44(exp4_pack(e2), exp4_pack(e3));
            acc[0][ns] = mfma32(cat44(va[0][0], va[0][1]), P01, acc[0][ns]);
            acc[0][ns] = mfma32(cat44(va[0][2], va[0][3]), P23, acc[0][ns]);
            acc[1][ns] = mfma32(cat44(va[1][0], va[1][1]), P01, acc[1][ns]);
            acc[1][ns] = mfma32(cat44(va[1][2], va[1][3]), P23, acc[1][ns]);
        }
        #pragma unroll
        for (int j = 0; j < 4; ++j) qa[j] = nqa[j];
        #pragma unroll
        for (int ds = 0; ds < 2; ++ds)
            #pragma unroll
            for (int j = 0; j < 4; ++j) va[ds][j] = nva[ds][j];
    }
    // epilogue: last 64-m step
    #pragma unroll
    for (int ns = 0; ns < 4; ++ns) {
        f32x4 e0 = mfma32(qa[0], kb[ns], zero4);
        f32x4 e1 = mfma32(qa[1], kb[ns], zero4);
        f32x4 e2 = mfma32(qa[2], kb[ns], zero4);
        f32x4 e3 = mfma32(qa[3], kb[ns], zero4);
        s16x8 P01 = cat44(exp4_pack(e0), exp4_pack(e1));
        s16x8 P23 = cat44(exp4_pack(e2), exp4_pack(e3));
        acc[0][ns] = mfma32(cat44(va[0][0], va[0][1]), P01, acc[0][ns]);
        acc[0][ns] = mfma32(cat44(va[0][2], va[0][3]), P23, acc[0][ns]);
        acc[1][ns] = mfma32(cat44(va[1][0], va[1][1]), P01, acc[1][ns]);
        acc[1][ns] = mfma32(cat44(va[1][2], va[1][3]), P23, acc[1][ns]);
    }

    float* af = (float*)acc;   // 32 contiguous f32
    if (wv > 0) {
        #pragma unroll
        for (int j = 0; j < 32; ++j) red[wv-1][j][lane] = af[j];
    }
    __syncthreads();
    if (wv == 0) {
        #pragma unroll
        for (int j = 0; j < 32; ++j)
            af[j] += red[0][j][lane] + red[1][j][lane] + red[2][j][lane];
        float* yb = y + (size_t)b * CC * HH * WW;
        #pragma unroll
        for (int ds = 0; ds < 2; ++ds) {
            #pragma unroll
            for (int ns = 0; ns < 4; ++ns) {
                #pragma unroll
                for (int rr = 0; rr < 4; ++rr) {
                    int dd = ds*16 + g*4 + rr;
                    if (dd < HD)
                        yb[((size_t)(dd*NH_ + nh))*NN + n0 + ns*16 + c] = acc[ds][ns][rr];
                }
            }
        }
    }
}

extern "C" void kernel_launch(void* const* d_in, const int* in_sizes, int n_in,
                              void* d_out, int out_size, void* d_ws, size_t ws_size,
                              hipStream_t stream)
{
    const float* x  = (const float*)d_in[0];
    const float* Wq = (const float*)d_in[1];
    const float* bq = (const float*)d_in[2];
    const float* Wk = (const float*)d_in[3];
    const float* bk = (const float*)d_in[4];
    const float* Wv = (const float*)d_in[5];
    const float* bv = (const float*)d_in[6];
    float* y = (float*)d_out;

    const size_t QT_E = (size_t)NBH * NN * HDP;      // 3,932,160 bf16
    unsigned short* qt  = (unsigned short*)d_ws;
    unsigned short* kt  = qt + QT_E;
    unsigned short* vt  = kt + QT_E;                 // quad-major raw V
    unsigned short* wqb = vt + QT_E;
    unsigned short* wkb = wqb + WW*WW;
    unsigned short* wvb = wkb + WW*WW;               // total ~23.8 MB

    // zero pads of qt/kt (incl. bias slots) and vt pad rows
    hipMemsetAsync(qt, 0, 3 * QT_E * sizeof(unsigned short), stream);

    wprep_kernel<<<dim3((WW*WW + 255)/256), dim3(256), 0, stream>>>(
        Wq, Wk, Wv, wqb, wkb, wvb);
    ones_kernel<<<dim3((NBH*NN)/256), dim3(256), 0, stream>>>(kt);
    proj_mfma_kernel<<<dim3(BB*ROWS/64), dim3(256), 0, stream>>>(
        x, wqb, wkb, wvb, bq, bk, bv, qt, kt, vt);
    zinv_kernel<<<dim3(NBH*(NN/64)), dim3(256), 0, stream>>>(qt, kt);
    attn_out_kernel<<<dim3(NBH*(NN/64)), dim3(256), 0, stream>>>(qt, kt, vt, y);
}

// Round 18
// 181.868 us; speedup vs baseline: 1.0699x; 1.0699x over previous
//
#include <hip/hip_runtime.h>
#include <hip/hip_bf16.h>
#include <math.h>

#define BB   4
#define CC   32
#define HH   120
#define WW   160
#define NH_  8
#define HD   20
#define HDP  32            // head dim padded to 32 (zeros) for K=32 MFMA
#define NN   3840          // sequence length (C*H)
#define ROWS 3840
#define NBH  32            // B * NH
#define LOG2E 1.44269504088896f

typedef float f32x4 __attribute__((ext_vector_type(4)));
typedef short s16x8 __attribute__((ext_vector_type(8)));
typedef short s16x4 __attribute__((ext_vector_type(4)));

static __device__ __forceinline__ unsigned short f2bf(float x) {
    return __builtin_bit_cast(unsigned short, __float2bfloat16(x));
}
static __device__ __forceinline__ float bf2f(unsigned short u) {
    unsigned v = ((unsigned)u) << 16;
    return __builtin_bit_cast(float, v);
}
static __device__ __forceinline__ float exp2fast(float x) {
#if defined(__has_builtin) && __has_builtin(__builtin_amdgcn_exp2f)
    return __builtin_amdgcn_exp2f(x);
#else
    float r; asm("v_exp_f32 %0, %1" : "=v"(r) : "v"(x)); return r;
#endif
}

// exp2 four lanes then pack to bf16 by TRUNCATION (R18: dropped the
// +0x8000 round-half-up adds — P>0 so truncation is a systematic -0.1-0.2%
// scale on out, within error budget; saves 64 VALU/step in the hot loop).
// BUILTIN-ONLY pack — perm path validated R5/R9-R17. Do NOT use the cvt_pk
// inline-asm variant (R7/R8 corruption in unrolled loops).
static __device__ __forceinline__ s16x4 exp4_pack(f32x4 e) {
    unsigned u0 = __builtin_bit_cast(unsigned, exp2fast(e[0]));
    unsigned u1 = __builtin_bit_cast(unsigned, exp2fast(e[1]));
    unsigned u2 = __builtin_bit_cast(unsigned, exp2fast(e[2]));
    unsigned u3 = __builtin_bit_cast(unsigned, exp2fast(e[3]));
    uint2 w;
#if defined(__has_builtin) && __has_builtin(__builtin_amdgcn_perm)
    w.x = __builtin_amdgcn_perm(u1, u0, 0x07060302u);
    w.y = __builtin_amdgcn_perm(u3, u2, 0x07060302u);
#else
    w.x = (u0 >> 16) | (u1 & 0xffff0000u);
    w.y = (u2 >> 16) | (u3 & 0xffff0000u);
#endif
    return __builtin_bit_cast(s16x4, w);
}

static __device__ __forceinline__ f32x4 mfma32(s16x8 a, s16x8 b, f32x4 c) {
    return __builtin_amdgcn_mfma_f32_16x16x32_bf16(a, b, c, 0, 0, 0);
}
// concat two s16x4 into a K=32 fragment half-pair (register pairing, no ops)
static __device__ __forceinline__ s16x8 cat44(s16x4 a, s16x4 b) {
    s16x8 r;
    r[0]=a[0]; r[1]=a[1]; r[2]=a[2]; r[3]=a[3];
    r[4]=b[0]; r[5]=b[1]; r[6]=b[2]; r[7]=b[3];
    return r;
}

// ---------------- W prep: f32 -> bf16 [o][k]; Wq pre-scaled by log2(e) ----
__global__ __launch_bounds__(256)
void wprep_kernel(const float* __restrict__ Wq, const float* __restrict__ Wk,
                  const float* __restrict__ Wv,
                  unsigned short* __restrict__ wqb, unsigned short* __restrict__ wkb,
                  unsigned short* __restrict__ wvb)
{
    int i = blockIdx.x*256 + threadIdx.x;
    if (i < WW*WW) {
        wqb[i] = f2bf(Wq[i] * LOG2E);
        wkb[i] = f2bf(Wk[i]);
        wvb[i] = f2bf(Wv[i]);
    }
}

// ---------------- Projection via MFMA (no LDS) ---------------------------
// R18 regrid: 480 blocks (was 240, 0.94/CU). Wave = 16 rows x 80 cols
// (half the n-tiles); block = 32 rows x 2 col-halves -> 1920 waves.
__global__ __launch_bounds__(256)
void proj_mfma_kernel(const float* __restrict__ x,
                      const unsigned short* __restrict__ wqb,
                      const unsigned short* __restrict__ wkb,
                      const unsigned short* __restrict__ wvb,
                      const float* __restrict__ bq, const float* __restrict__ bk,
                      const float* __restrict__ bv,
                      unsigned short* __restrict__ qt, unsigned short* __restrict__ kt,
                      unsigned short* __restrict__ vb)
{
    const int tid  = threadIdx.x;
    const int wv   = tid >> 6;
    const int lane = tid & 63;
    const int g = lane >> 4, c = lane & 15;
    const int r0 = blockIdx.x*32 + (wv & 1)*16;   // wave's 16-row tile
    const int ch = wv >> 1;                        // col half: tiles ch*5..ch*5+4

    s16x8 A[5];
    const float* xrow = x + (size_t)(r0 + c)*WW;
    #pragma unroll
    for (int s = 0; s < 5; ++s) {
        float4 v0 = *(const float4*)(xrow + s*32 + g*8);
        float4 v1 = *(const float4*)(xrow + s*32 + g*8 + 4);
        s16x8 a;
        a[0]=(short)f2bf(v0.x); a[1]=(short)f2bf(v0.y);
        a[2]=(short)f2bf(v0.z); a[3]=(short)f2bf(v0.w);
        a[4]=(short)f2bf(v1.x); a[5]=(short)f2bf(v1.y);
        a[6]=(short)f2bf(v1.z); a[7]=(short)f2bf(v1.w);
        A[s] = a;
    }

    size_t baseqk[4], basev[4];
    #pragma unroll
    for (int rr = 0; rr < 4; ++rr) {
        int R  = r0 + g*4 + rr;
        int b  = R / ROWS;
        int r  = R % ROWS;
        int nh = r / 480;
        int rm = r % 480;
        int d  = rm / 24;
        int n1 = rm % 24;
        int bh = b*NH_ + nh;
        baseqk[rr] = ((size_t)bh*NN + n1*160)*HDP + d;
        basev[rr]  = ((size_t)bh*HD + d)*NN + n1*160;
    }

    const f32x4 zero4 = {0.f, 0.f, 0.f, 0.f};
    for (int nt = ch*5; nt < ch*5 + 5; ++nt) {
        const size_t wbase = (size_t)(nt*16 + c)*WW;
        f32x4 aq = zero4, ak = zero4, av = zero4;
        #pragma unroll
        for (int s = 0; s < 5; ++s) {
            s16x8 Bq = *(const s16x8*)(wqb + wbase + s*32 + g*8);
            aq = mfma32(A[s], Bq, aq);
            s16x8 Bk = *(const s16x8*)(wkb + wbase + s*32 + g*8);
            ak = mfma32(A[s], Bk, ak);
            s16x8 Bv = *(const s16x8*)(wvb + wbase + s*32 + g*8);
            av = mfma32(A[s], Bv, av);
        }
        const int o = nt*16 + c;
        const float bqv = bq[o]*LOG2E, bkv = bk[o], bvv = bv[o];
        #pragma unroll
        for (int rr = 0; rr < 4; ++rr) {
            qt[baseqk[rr] + (size_t)o*HDP] = f2bf(aq[rr] + bqv);
            kt[baseqk[rr] + (size_t)o*HDP] = f2bf(ak[rr] + bkv);
            vb[basev[rr] + o]              = f2bf(av[rr] + bvv);
        }
    }
}

// ---------------- Pass 1: zinv[m] = 1 / sum_n exp2(E[m,n]) ---------------
// R12-exact (passing): 1920 blocks, XCD swizzle, 1-deep K prefetch.
__global__ __launch_bounds__(256, 4)
void zinv_kernel(const unsigned short* __restrict__ qt,
                 const unsigned short* __restrict__ kt,
                 float* __restrict__ zinv)
{
    __shared__ float zred[4][64];
    const int blk  = ((int)blockIdx.x & 7) * (NBH*(NN/64)/8) + ((int)blockIdx.x >> 3);
    const int bh   = blk / (NN/64);
    const int m0   = (blk % (NN/64)) * 64;
    const int tid  = threadIdx.x;
    const int wv   = tid >> 6;
    const int lane = tid & 63;
    const int g = lane >> 4, c = lane & 15;

    s16x8 qa[4];
    #pragma unroll
    for (int ms = 0; ms < 4; ++ms)
        qa[ms] = *(const s16x8*)(qt + ((size_t)bh*NN + m0 + ms*16 + c)*HDP + g*8);

    const f32x4 zero4 = {0.f, 0.f, 0.f, 0.f};
    f32x4 z[4];
    #pragma unroll
    for (int ms = 0; ms < 4; ++ms) z[ms] = zero4;

    const unsigned short* kbase = kt + (size_t)bh*NN*HDP;
    const int nbeg = wv * (NN/4);
    const int nend = nbeg + NN/4;

    s16x8 kb0 = *(const s16x8*)(kbase + (size_t)(nbeg +      c)*HDP + g*8);
    s16x8 kb1 = *(const s16x8*)(kbase + (size_t)(nbeg + 16 + c)*HDP + g*8);

    for (int n = nbeg; n < nend - 32; n += 32) {
        s16x8 nk0 = *(const s16x8*)(kbase + (size_t)(n + 32 +      c)*HDP + g*8);
        s16x8 nk1 = *(const s16x8*)(kbase + (size_t)(n + 48 +      c)*HDP + g*8);
        #pragma unroll
        for (int ms = 0; ms < 4; ++ms) {
            f32x4 e0 = mfma32(qa[ms], kb0, zero4);
            f32x4 e1 = mfma32(qa[ms], kb1, zero4);
            #pragma unroll
            for (int rr = 0; rr < 4; ++rr)
                z[ms][rr] += exp2fast(e0[rr]) + exp2fast(e1[rr]);
        }
        kb0 = nk0; kb1 = nk1;
    }
    #pragma unroll
    for (int ms = 0; ms < 4; ++ms) {
        f32x4 e0 = mfma32(qa[ms], kb0, zero4);
        f32x4 e1 = mfma32(qa[ms], kb1, zero4);
        #pragma unroll
        for (int rr = 0; rr < 4; ++rr)
            z[ms][rr] += exp2fast(e0[rr]) + exp2fast(e1[rr]);
    }

    #pragma unroll
    for (int ms = 0; ms < 4; ++ms) {
        #pragma unroll
        for (int rr = 0; rr < 4; ++rr) {
            float v = z[ms][rr];
            v += __shfl_xor(v, 1);
            v += __shfl_xor(v, 2);
            v += __shfl_xor(v, 4);
            v += __shfl_xor(v, 8);
            if (c == 0) zred[wv][ms*16 + g*4 + rr] = v;
        }
    }
    __syncthreads();
    if (tid < 64) {
        float s = zred[0][tid] + zred[1][tid] + zred[2][tid] + zred[3][tid];
        zinv[(size_t)bh*NN + m0 + tid] = 1.0f / s;
    }
}

// ---------------- vzt: quad-major Vz (multiply + relayout, R16-exact) ----
// vzt[bh][q=m/4][dp][m%4] bf16. Coalesced 8B writes across dp; gather reads
// from L2-resident vb/zinv.
__global__ __launch_bounds__(256)
void vz_kernel(const unsigned short* __restrict__ vb,
               const float* __restrict__ zinv,
               unsigned short* __restrict__ vzt)
{
    size_t idx = (size_t)blockIdx.x*256 + threadIdx.x;   // over NBH*(NN/4)*HDP
    int dp = (int)(idx % HDP);
    size_t t = idx / HDP;
    int q  = (int)(t % (NN/4));
    int bh = (int)(t / (NN/4));
    float v0=0.f, v1=0.f, v2=0.f, v3=0.f;
    if (dp < HD) {
        const unsigned short* src = vb + ((size_t)bh*HD + dp)*NN + q*4;
        const float* zi = zinv + (size_t)bh*NN + q*4;
        v0 = bf2f(src[0])*zi[0];
        v1 = bf2f(src[1])*zi[1];
        v2 = bf2f(src[2])*zi[2];
        v3 = bf2f(src[3])*zi[3];
    }
    s16x4 o;
    o[0]=(short)f2bf(v0); o[1]=(short)f2bf(v1);
    o[2]=(short)f2bf(v2); o[3]=(short)f2bf(v3);
    *(s16x4*)(vzt + (size_t)bh*HDP*NN + (size_t)q*(HDP*4) + dp*4) = o;
}

// ---------------- Pass 2: out = Vz * exp2(Q^T K) ------------------------
// R16-exact body (passing, 90.6us); only change: truncation exp4_pack.
__global__ __launch_bounds__(256, 3)
void attn_out_kernel(const unsigned short* __restrict__ qt,
                     const unsigned short* __restrict__ kt,
                     const unsigned short* __restrict__ vzt,
                     float* __restrict__ y)
{
    __shared__ float red[3][32][64];   // 24 KB
    const int blk  = ((int)blockIdx.x & 7) * (NBH*(NN/64)/8) + ((int)blockIdx.x >> 3);
    const int bh   = blk / (NN/64);
    const int n0   = (blk % (NN/64)) * 64;
    const int tid  = threadIdx.x;
    const int wv   = tid >> 6;
    const int lane = tid & 63;
    const int g = lane >> 4, c = lane & 15;
    const int b = bh >> 3, nh = bh & 7;

    const f32x4 zero4 = {0.f, 0.f, 0.f, 0.f};
    const unsigned short* qb  = qt  + (size_t)bh*NN*HDP;
    const unsigned short* kbp = kt  + (size_t)bh*NN*HDP;
    const unsigned short* vp  = vzt + (size_t)bh*HDP*NN;

    s16x8 kb[4];
    #pragma unroll
    for (int ns = 0; ns < 4; ++ns)
        kb[ns] = *(const s16x8*)(kbp + ((size_t)(n0 + ns*16 + c))*HDP + g*8);

    f32x4 acc[2][4];
    #pragma unroll
    for (int ds = 0; ds < 2; ++ds)
        #pragma unroll
        for (int ns = 0; ns < 4; ++ns) acc[ds][ns] = zero4;

    const int mbeg = wv * (NN/4);          // 960 m per wave = 15 steps of 64
    const int mend = mbeg + NN/4;

    s16x8 qa[4];
    s16x4 va[2][4];
    #pragma unroll
    for (int j = 0; j < 4; ++j)
        qa[j] = *(const s16x8*)(qb + ((size_t)(mbeg + j*16 + c))*HDP + g*8);
    #pragma unroll
    for (int ds = 0; ds < 2; ++ds)
        #pragma unroll
        for (int j = 0; j < 4; ++j)
            va[ds][j] = *(const s16x4*)(vp + (size_t)((mbeg >> 2) + j*4 + g)*(HDP*4)
                                           + (ds*16 + c)*4);

    for (int m0 = mbeg; m0 < mend - 64; m0 += 64) {
        const int m1 = m0 + 64;
        s16x8 nqa[4];
        s16x4 nva[2][4];
        #pragma unroll
        for (int j = 0; j < 4; ++j)
            nqa[j] = *(const s16x8*)(qb + ((size_t)(m1 + j*16 + c))*HDP + g*8);
        #pragma unroll
        for (int ds = 0; ds < 2; ++ds)
            #pragma unroll
            for (int j = 0; j < 4; ++j)
                nva[ds][j] = *(const s16x4*)(vp + (size_t)((m1 >> 2) + j*4 + g)*(HDP*4)
                                                + (ds*16 + c)*4);

        #pragma unroll
        for (int ns = 0; ns < 4; ++ns) {
            f32x4 e0 = mfma32(qa[0], kb[ns], zero4);
            f32x4 e1 = mfma32(qa[1], kb[ns], zero4);
            f32x4 e2 = mfma32(qa[2], kb[ns], zero4);
            f32x4 e3 = mfma32(qa[3], kb[ns], zero4);
            s16x8 P01 = cat44(exp4_pack(e0), exp4_pack(e1));   // pi order
            s16x8 P23 = cat44(exp4_pack(e2), exp4_pack(e3));
            acc[0][ns] = mfma32(cat44(va[0][0], va[0][1]), P01, acc[0][ns]);
            acc[0][ns] = mfma32(cat44(va[0][2], va[0][3]), P23, acc[0][ns]);
            acc[1][ns] = mfma32(cat44(va[1][0], va[1][1]), P01, acc[1][ns]);
            acc[1][ns] = mfma32(cat44(va[1][2], va[1][3]), P23, acc[1][ns]);
        }
        #pragma unroll
        for (int j = 0; j < 4; ++j) qa[j] = nqa[j];
        #pragma unroll
        for (int ds = 0; ds < 2; ++ds)
            #pragma unroll
            for (int j = 0; j < 4; ++j) va[ds][j] = nva[ds][j];
    }
    // epilogue: last 64-m step
    #pragma unroll
    for (int ns = 0; ns < 4; ++ns) {
        f32x4 e0 = mfma32(qa[0], kb[ns], zero4);
        f32x4 e1 = mfma32(qa[1], kb[ns], zero4);
        f32x4 e2 = mfma32(qa[2], kb[ns], zero4);
        f32x4 e3 = mfma32(qa[3], kb[ns], zero4);
        s16x8 P01 = cat44(exp4_pack(e0), exp4_pack(e1));
        s16x8 P23 = cat44(exp4_pack(e2), exp4_pack(e3));
        acc[0][ns] = mfma32(cat44(va[0][0], va[0][1]), P01, acc[0][ns]);
        acc[0][ns] = mfma32(cat44(va[0][2], va[0][3]), P23, acc[0][ns]);
        acc[1][ns] = mfma32(cat44(va[1][0], va[1][1]), P01, acc[1][ns]);
        acc[1][ns] = mfma32(cat44(va[1][2], va[1][3]), P23, acc[1][ns]);
    }

    float* af = (float*)acc;   // 32 contiguous f32
    if (wv > 0) {
        #pragma unroll
        for (int j = 0; j < 32; ++j) red[wv-1][j][lane] = af[j];
    }
    __syncthreads();
    if (wv == 0) {
        #pragma unroll
        for (int j = 0; j < 32; ++j)
            af[j] += red[0][j][lane] + red[1][j][lane] + red[2][j][lane];
        float* yb = y + (size_t)b * CC * HH * WW;
        #pragma unroll
        for (int ds = 0; ds < 2; ++ds) {
            #pragma unroll
            for (int ns = 0; ns < 4; ++ns) {
                #pragma unroll
                for (int rr = 0; rr < 4; ++rr) {
                    int dd = ds*16 + g*4 + rr;
                    if (dd < HD)
                        yb[((size_t)(dd*NH_ + nh))*NN + n0 + ns*16 + c] = acc[ds][ns][rr];
                }
            }
        }
    }
}

extern "C" void kernel_launch(void* const* d_in, const int* in_sizes, int n_in,
                              void* d_out, int out_size, void* d_ws, size_t ws_size,
                              hipStream_t stream)
{
    const float* x  = (const float*)d_in[0];
    const float* Wq = (const float*)d_in[1];
    const float* bq = (const float*)d_in[2];
    const float* Wk = (const float*)d_in[3];
    const float* bk = (const float*)d_in[4];
    const float* Wv = (const float*)d_in[5];
    const float* bv = (const float*)d_in[6];
    float* y = (float*)d_out;

    const size_t QT_E = (size_t)NBH * NN * HDP;      // 3,932,160 bf16
    unsigned short* qt  = (unsigned short*)d_ws;
    unsigned short* kt  = qt + QT_E;
    unsigned short* vb  = kt + QT_E;
    unsigned short* vzt = vb + (size_t)NBH * HD * NN;
    float*          zinv = (float*)(vzt + QT_E);
    unsigned short* wqb = (unsigned short*)(zinv + (size_t)NBH*NN);
    unsigned short* wkb = wqb + WW*WW;
    unsigned short* wvb = wkb + WW*WW;               // total ~29.2 MB

    hipMemsetAsync(qt, 0, 2 * QT_E * sizeof(unsigned short), stream);

    wprep_kernel<<<dim3((WW*WW + 255)/256), dim3(256), 0, stream>>>(
        Wq, Wk, Wv, wqb, wkb, wvb);
    proj_mfma_kernel<<<dim3(BB*ROWS/32), dim3(256), 0, stream>>>(
        x, wqb, wkb, wvb, bq, bk, bv, qt, kt, vb);
    zinv_kernel<<<dim3(NBH*(NN/64)), dim3(256), 0, stream>>>(qt, kt, zinv);
    vz_kernel<<<dim3((NBH*(NN/4)*HDP)/256), dim3(256), 0, stream>>>(vb, zinv, vzt);
    attn_out_kernel<<<dim3(NBH*(NN/64)), dim3(256), 0, stream>>>(qt, kt, vzt, y);
}

// Round 19
// 179.033 us; speedup vs baseline: 1.0869x; 1.0158x over previous
//
#include <hip/hip_runtime.h>
#include <hip/hip_bf16.h>
#include <math.h>

#define BB   4
#define CC   32
#define HH   120
#define WW   160
#define NH_  8
#define HD   20
#define HDP  32            // head dim padded to 32 (zeros) for K=32 MFMA
#define NN   3840          // sequence length (C*H)
#define ROWS 3840
#define NBH  32            // B * NH
#define LOG2E 1.44269504088896f

typedef float f32x4 __attribute__((ext_vector_type(4)));
typedef short s16x8 __attribute__((ext_vector_type(8)));
typedef short s16x4 __attribute__((ext_vector_type(4)));

static __device__ __forceinline__ unsigned short f2bf(float x) {
    return __builtin_bit_cast(unsigned short, __float2bfloat16(x));
}
static __device__ __forceinline__ float bf2f(unsigned short u) {
    unsigned v = ((unsigned)u) << 16;
    return __builtin_bit_cast(float, v);
}
static __device__ __forceinline__ float exp2fast(float x) {
#if defined(__has_builtin) && __has_builtin(__builtin_amdgcn_exp2f)
    return __builtin_amdgcn_exp2f(x);
#else
    float r; asm("v_exp_f32 %0, %1" : "=v"(r) : "v"(x)); return r;
#endif
}

// exp2 four lanes then pack to bf16 by TRUNCATION (validated R18:
// absmax 0.0176 < 0.0306). BUILTIN-ONLY pack — perm path validated
// R5/R9-R18. Do NOT use the cvt_pk inline-asm variant (R7/R8 corruption).
static __device__ __forceinline__ s16x4 exp4_pack(f32x4 e) {
    unsigned u0 = __builtin_bit_cast(unsigned, exp2fast(e[0]));
    unsigned u1 = __builtin_bit_cast(unsigned, exp2fast(e[1]));
    unsigned u2 = __builtin_bit_cast(unsigned, exp2fast(e[2]));
    unsigned u3 = __builtin_bit_cast(unsigned, exp2fast(e[3]));
    uint2 w;
#if defined(__has_builtin) && __has_builtin(__builtin_amdgcn_perm)
    w.x = __builtin_amdgcn_perm(u1, u0, 0x07060302u);
    w.y = __builtin_amdgcn_perm(u3, u2, 0x07060302u);
#else
    w.x = (u0 >> 16) | (u1 & 0xffff0000u);
    w.y = (u2 >> 16) | (u3 & 0xffff0000u);
#endif
    return __builtin_bit_cast(s16x4, w);
}

static __device__ __forceinline__ f32x4 mfma32(s16x8 a, s16x8 b, f32x4 c) {
    return __builtin_amdgcn_mfma_f32_16x16x32_bf16(a, b, c, 0, 0, 0);
}
// concat two s16x4 into a K=32 fragment half-pair (register pairing, no ops)
static __device__ __forceinline__ s16x8 cat44(s16x4 a, s16x4 b) {
    s16x8 r;
    r[0]=a[0]; r[1]=a[1]; r[2]=a[2]; r[3]=a[3];
    r[4]=b[0]; r[5]=b[1]; r[6]=b[2]; r[7]=b[3];
    return r;
}

// ---------------- W prep: f32 -> bf16 [o][k]; Wq pre-scaled by log2(e) ----
__global__ __launch_bounds__(256)
void wprep_kernel(const float* __restrict__ Wq, const float* __restrict__ Wk,
                  const float* __restrict__ Wv,
                  unsigned short* __restrict__ wqb, unsigned short* __restrict__ wkb,
                  unsigned short* __restrict__ wvb)
{
    int i = blockIdx.x*256 + threadIdx.x;
    if (i < WW*WW) {
        wqb[i] = f2bf(Wq[i] * LOG2E);
        wkb[i] = f2bf(Wk[i]);
        wvb[i] = f2bf(Wv[i]);
    }
}

// ---------------- Projection via MFMA (no LDS), R18 regrid ---------------
__global__ __launch_bounds__(256)
void proj_mfma_kernel(const float* __restrict__ x,
                      const unsigned short* __restrict__ wqb,
                      const unsigned short* __restrict__ wkb,
                      const unsigned short* __restrict__ wvb,
                      const float* __restrict__ bq, const float* __restrict__ bk,
                      const float* __restrict__ bv,
                      unsigned short* __restrict__ qt, unsigned short* __restrict__ kt,
                      unsigned short* __restrict__ vb)
{
    const int tid  = threadIdx.x;
    const int wv   = tid >> 6;
    const int lane = tid & 63;
    const int g = lane >> 4, c = lane & 15;
    const int r0 = blockIdx.x*32 + (wv & 1)*16;   // wave's 16-row tile
    const int ch = wv >> 1;                        // col half: tiles ch*5..ch*5+4

    s16x8 A[5];
    const float* xrow = x + (size_t)(r0 + c)*WW;
    #pragma unroll
    for (int s = 0; s < 5; ++s) {
        float4 v0 = *(const float4*)(xrow + s*32 + g*8);
        float4 v1 = *(const float4*)(xrow + s*32 + g*8 + 4);
        s16x8 a;
        a[0]=(short)f2bf(v0.x); a[1]=(short)f2bf(v0.y);
        a[2]=(short)f2bf(v0.z); a[3]=(short)f2bf(v0.w);
        a[4]=(short)f2bf(v1.x); a[5]=(short)f2bf(v1.y);
        a[6]=(short)f2bf(v1.z); a[7]=(short)f2bf(v1.w);
        A[s] = a;
    }

    size_t baseqk[4], basev[4];
    #pragma unroll
    for (int rr = 0; rr < 4; ++rr) {
        int R  = r0 + g*4 + rr;
        int b  = R / ROWS;
        int r  = R % ROWS;
        int nh = r / 480;
        int rm = r % 480;
        int d  = rm / 24;
        int n1 = rm % 24;
        int bh = b*NH_ + nh;
        baseqk[rr] = ((size_t)bh*NN + n1*160)*HDP + d;
        basev[rr]  = ((size_t)bh*HD + d)*NN + n1*160;
    }

    const f32x4 zero4 = {0.f, 0.f, 0.f, 0.f};
    for (int nt = ch*5; nt < ch*5 + 5; ++nt) {
        const size_t wbase = (size_t)(nt*16 + c)*WW;
        f32x4 aq = zero4, ak = zero4, av = zero4;
        #pragma unroll
        for (int s = 0; s < 5; ++s) {
            s16x8 Bq = *(const s16x8*)(wqb + wbase + s*32 + g*8);
            aq = mfma32(A[s], Bq, aq);
            s16x8 Bk = *(const s16x8*)(wkb + wbase + s*32 + g*8);
            ak = mfma32(A[s], Bk, ak);
            s16x8 Bv = *(const s16x8*)(wvb + wbase + s*32 + g*8);
            av = mfma32(A[s], Bv, av);
        }
        const int o = nt*16 + c;
        const float bqv = bq[o]*LOG2E, bkv = bk[o], bvv = bv[o];
        #pragma unroll
        for (int rr = 0; rr < 4; ++rr) {
            qt[baseqk[rr] + (size_t)o*HDP] = f2bf(aq[rr] + bqv);
            kt[baseqk[rr] + (size_t)o*HDP] = f2bf(ak[rr] + bkv);
            vb[basev[rr] + o]              = f2bf(av[rr] + bvv);
        }
    }
}

// ---------------- Pass 1 (fused): Z + quad-major Vz ----------------------
// R12-exact E/exp body -> Z for this block's 64 m; then the SAME block
// produces vzt[bh][q][dp][m%4] for its m-range (thread = (dp, m-octet):
// 16B contiguous vb read = one 128B line per dp-row; coalesced 8B writes;
// zeros for pad dp). Deletes the vz kernel + zinv[] round-trip.
__global__ __launch_bounds__(256, 4)
void zinv_kernel(const unsigned short* __restrict__ qt,
                 const unsigned short* __restrict__ kt,
                 const unsigned short* __restrict__ vb,
                 unsigned short* __restrict__ vzt)
{
    __shared__ float zred[4][64];
    const int blk  = ((int)blockIdx.x & 7) * (NBH*(NN/64)/8) + ((int)blockIdx.x >> 3);
    const int bh   = blk / (NN/64);
    const int m0   = (blk % (NN/64)) * 64;
    const int tid  = threadIdx.x;
    const int wv   = tid >> 6;
    const int lane = tid & 63;
    const int g = lane >> 4, c = lane & 15;

    s16x8 qa[4];
    #pragma unroll
    for (int ms = 0; ms < 4; ++ms)
        qa[ms] = *(const s16x8*)(qt + ((size_t)bh*NN + m0 + ms*16 + c)*HDP + g*8);

    const f32x4 zero4 = {0.f, 0.f, 0.f, 0.f};
    f32x4 z[4];
    #pragma unroll
    for (int ms = 0; ms < 4; ++ms) z[ms] = zero4;

    const unsigned short* kbase = kt + (size_t)bh*NN*HDP;
    const int nbeg = wv * (NN/4);
    const int nend = nbeg + NN/4;

    s16x8 kb0 = *(const s16x8*)(kbase + (size_t)(nbeg +      c)*HDP + g*8);
    s16x8 kb1 = *(const s16x8*)(kbase + (size_t)(nbeg + 16 + c)*HDP + g*8);

    for (int n = nbeg; n < nend - 32; n += 32) {
        s16x8 nk0 = *(const s16x8*)(kbase + (size_t)(n + 32 +      c)*HDP + g*8);
        s16x8 nk1 = *(const s16x8*)(kbase + (size_t)(n + 48 +      c)*HDP + g*8);
        #pragma unroll
        for (int ms = 0; ms < 4; ++ms) {
            f32x4 e0 = mfma32(qa[ms], kb0, zero4);
            f32x4 e1 = mfma32(qa[ms], kb1, zero4);
            #pragma unroll
            for (int rr = 0; rr < 4; ++rr)
                z[ms][rr] += exp2fast(e0[rr]) + exp2fast(e1[rr]);
        }
        kb0 = nk0; kb1 = nk1;
    }
    #pragma unroll
    for (int ms = 0; ms < 4; ++ms) {
        f32x4 e0 = mfma32(qa[ms], kb0, zero4);
        f32x4 e1 = mfma32(qa[ms], kb1, zero4);
        #pragma unroll
        for (int rr = 0; rr < 4; ++rr)
            z[ms][rr] += exp2fast(e0[rr]) + exp2fast(e1[rr]);
    }

    #pragma unroll
    for (int ms = 0; ms < 4; ++ms) {
        #pragma unroll
        for (int rr = 0; rr < 4; ++rr) {
            float v = z[ms][rr];
            v += __shfl_xor(v, 1);
            v += __shfl_xor(v, 2);
            v += __shfl_xor(v, 4);
            v += __shfl_xor(v, 8);
            if (c == 0) zred[wv][ms*16 + g*4 + rr] = v;
        }
    }
    __syncthreads();
    if (tid < 64) {
        float s = zred[0][tid] + zred[1][tid] + zred[2][tid] + zred[3][tid];
        zred[0][tid] = 1.0f / s;      // same-thread RMW of own slot: safe
    }
    __syncthreads();

    // fused Vz: thread = (dp = tid&31, half = tid>>5); m-sub = half*8
    {
        const int dp   = tid & 31;
        const int half = tid >> 5;
        const int mloc = half * 8;
        unsigned short pv[8];
        if (dp < HD) {
            const unsigned short* src = vb + ((size_t)bh*HD + dp)*NN + m0 + mloc;
            s16x8 raw = *(const s16x8*)src;    // 16B contiguous, aligned
            #pragma unroll
            for (int j = 0; j < 8; ++j)
                pv[j] = f2bf(bf2f((unsigned short)raw[j]) * zred[0][mloc + j]);
        } else {
            #pragma unroll
            for (int j = 0; j < 8; ++j) pv[j] = 0;
        }
        unsigned short* dst = vzt + (size_t)bh*HDP*NN
                                  + (size_t)(m0/4 + half*2)*(HDP*4) + dp*4;
        s16x4 o0, o1;
        o0[0]=(short)pv[0]; o0[1]=(short)pv[1]; o0[2]=(short)pv[2]; o0[3]=(short)pv[3];
        o1[0]=(short)pv[4]; o1[1]=(short)pv[5]; o1[2]=(short)pv[6]; o1[3]=(short)pv[7];
        *(s16x4*)dst = o0;
        *(s16x4*)(dst + HDP*4) = o1;
    }
}

// ---------------- Pass 2: out = Vz * exp2(Q^T K) ------------------------
// R18-exact body (passing, 78.8us); only delta: s_setprio(1) around the
// MFMA+exp compute cluster (T5 — attn-positive regime: no in-loop barriers,
// waves at different phases).
__global__ __launch_bounds__(256, 3)
void attn_out_kernel(const unsigned short* __restrict__ qt,
                     const unsigned short* __restrict__ kt,
                     const unsigned short* __restrict__ vzt,
                     float* __restrict__ y)
{
    __shared__ float red[3][32][64];   // 24 KB
    const int blk  = ((int)blockIdx.x & 7) * (NBH*(NN/64)/8) + ((int)blockIdx.x >> 3);
    const int bh   = blk / (NN/64);
    const int n0   = (blk % (NN/64)) * 64;
    const int tid  = threadIdx.x;
    const int wv   = tid >> 6;
    const int lane = tid & 63;
    const int g = lane >> 4, c = lane & 15;
    const int b = bh >> 3, nh = bh & 7;

    const f32x4 zero4 = {0.f, 0.f, 0.f, 0.f};
    const unsigned short* qb  = qt  + (size_t)bh*NN*HDP;
    const unsigned short* kbp = kt  + (size_t)bh*NN*HDP;
    const unsigned short* vp  = vzt + (size_t)bh*HDP*NN;

    s16x8 kb[4];
    #pragma unroll
    for (int ns = 0; ns < 4; ++ns)
        kb[ns] = *(const s16x8*)(kbp + ((size_t)(n0 + ns*16 + c))*HDP + g*8);

    f32x4 acc[2][4];
    #pragma unroll
    for (int ds = 0; ds < 2; ++ds)
        #pragma unroll
        for (int ns = 0; ns < 4; ++ns) acc[ds][ns] = zero4;

    const int mbeg = wv * (NN/4);          // 960 m per wave = 15 steps of 64
    const int mend = mbeg + NN/4;

    s16x8 qa[4];
    s16x4 va[2][4];
    #pragma unroll
    for (int j = 0; j < 4; ++j)
        qa[j] = *(const s16x8*)(qb + ((size_t)(mbeg + j*16 + c))*HDP + g*8);
    #pragma unroll
    for (int ds = 0; ds < 2; ++ds)
        #pragma unroll
        for (int j = 0; j < 4; ++j)
            va[ds][j] = *(const s16x4*)(vp + (size_t)((mbeg >> 2) + j*4 + g)*(HDP*4)
                                           + (ds*16 + c)*4);

    for (int m0 = mbeg; m0 < mend - 64; m0 += 64) {
        const int m1 = m0 + 64;
        s16x8 nqa[4];
        s16x4 nva[2][4];
        #pragma unroll
        for (int j = 0; j < 4; ++j)
            nqa[j] = *(const s16x8*)(qb + ((size_t)(m1 + j*16 + c))*HDP + g*8);
        #pragma unroll
        for (int ds = 0; ds < 2; ++ds)
            #pragma unroll
            for (int j = 0; j < 4; ++j)
                nva[ds][j] = *(const s16x4*)(vp + (size_t)((m1 >> 2) + j*4 + g)*(HDP*4)
                                                + (ds*16 + c)*4);

        __builtin_amdgcn_s_setprio(1);
        #pragma unroll
        for (int ns = 0; ns < 4; ++ns) {
            f32x4 e0 = mfma32(qa[0], kb[ns], zero4);
            f32x4 e1 = mfma32(qa[1], kb[ns], zero4);
            f32x4 e2 = mfma32(qa[2], kb[ns], zero4);
            f32x4 e3 = mfma32(qa[3], kb[ns], zero4);
            s16x8 P01 = cat44(exp4_pack(e0), exp4_pack(e1));   // pi order
            s16x8 P23 = cat44(exp4_pack(e2), exp4_pack(e3));
            acc[0][ns] = mfma32(cat44(va[0][0], va[0][1]), P01, acc[0][ns]);
            acc[0][ns] = mfma32(cat44(va[0][2], va[0][3]), P23, acc[0][ns]);
            acc[1][ns] = mfma32(cat44(va[1][0], va[1][1]), P01, acc[1][ns]);
            acc[1][ns] = mfma32(cat44(va[1][2], va[1][3]), P23, acc[1][ns]);
        }
        __builtin_amdgcn_s_setprio(0);
        #pragma unroll
        for (int j = 0; j < 4; ++j) qa[j] = nqa[j];
        #pragma unroll
        for (int ds = 0; ds < 2; ++ds)
            #pragma unroll
            for (int j = 0; j < 4; ++j) va[ds][j] = nva[ds][j];
    }
    // epilogue: last 64-m step
    __builtin_amdgcn_s_setprio(1);
    #pragma unroll
    for (int ns = 0; ns < 4; ++ns) {
        f32x4 e0 = mfma32(qa[0], kb[ns], zero4);
        f32x4 e1 = mfma32(qa[1], kb[ns], zero4);
        f32x4 e2 = mfma32(qa[2], kb[ns], zero4);
        f32x4 e3 = mfma32(qa[3], kb[ns], zero4);
        s16x8 P01 = cat44(exp4_pack(e0), exp4_pack(e1));
        s16x8 P23 = cat44(exp4_pack(e2), exp4_pack(e3));
        acc[0][ns] = mfma32(cat44(va[0][0], va[0][1]), P01, acc[0][ns]);
        acc[0][ns] = mfma32(cat44(va[0][2], va[0][3]), P23, acc[0][ns]);
        acc[1][ns] = mfma32(cat44(va[1][0], va[1][1]), P01, acc[1][ns]);
        acc[1][ns] = mfma32(cat44(va[1][2], va[1][3]), P23, acc[1][ns]);
    }
    __builtin_amdgcn_s_setprio(0);

    float* af = (float*)acc;   // 32 contiguous f32
    if (wv > 0) {
        #pragma unroll
        for (int j = 0; j < 32; ++j) red[wv-1][j][lane] = af[j];
    }
    __syncthreads();
    if (wv == 0) {
        #pragma unroll
        for (int j = 0; j < 32; ++j)
            af[j] += red[0][j][lane] + red[1][j][lane] + red[2][j][lane];
        float* yb = y + (size_t)b * CC * HH * WW;
        #pragma unroll
        for (int ds = 0; ds < 2; ++ds) {
            #pragma unroll
            for (int ns = 0; ns < 4; ++ns) {
                #pragma unroll
                for (int rr = 0; rr < 4; ++rr) {
                    int dd = ds*16 + g*4 + rr;
                    if (dd < HD)
                        yb[((size_t)(dd*NH_ + nh))*NN + n0 + ns*16 + c] = acc[ds][ns][rr];
                }
            }
        }
    }
}

extern "C" void kernel_launch(void* const* d_in, const int* in_sizes, int n_in,
                              void* d_out, int out_size, void* d_ws, size_t ws_size,
                              hipStream_t stream)
{
    const float* x  = (const float*)d_in[0];
    const float* Wq = (const float*)d_in[1];
    const float* bq = (const float*)d_in[2];
    const float* Wk = (const float*)d_in[3];
    const float* bk = (const float*)d_in[4];
    const float* Wv = (const float*)d_in[5];
    const float* bv = (const float*)d_in[6];
    float* y = (float*)d_out;

    const size_t QT_E = (size_t)NBH * NN * HDP;      // 3,932,160 bf16
    unsigned short* qt  = (unsigned short*)d_ws;
    unsigned short* kt  = qt + QT_E;
    unsigned short* vb  = kt + QT_E;
    unsigned short* vzt = vb + (size_t)NBH * HD * NN;
    unsigned short* wqb = vzt + QT_E;
    unsigned short* wkb = wqb + WW*WW;
    unsigned short* wvb = wkb + WW*WW;               // total ~28.7 MB

    hipMemsetAsync(qt, 0, 2 * QT_E * sizeof(unsigned short), stream);

    wprep_kernel<<<dim3((WW*WW + 255)/256), dim3(256), 0, stream>>>(
        Wq, Wk, Wv, wqb, wkb, wvb);
    proj_mfma_kernel<<<dim3(BB*ROWS/32), dim3(256), 0, stream>>>(
        x, wqb, wkb, wvb, bq, bk, bv, qt, kt, vb);
    zinv_kernel<<<dim3(NBH*(NN/64)), dim3(256), 0, stream>>>(qt, kt, vb, vzt);
    attn_out_kernel<<<dim3(NBH*(NN/64)), dim3(256), 0, stream>>>(qt, kt, vzt, y);
}

// Round 20
// 174.502 us; speedup vs baseline: 1.1151x; 1.0260x over previous
//
#include <hip/hip_runtime.h>
#include <hip/hip_bf16.h>
#include <math.h>

#define BB   4
#define CC   32
#define HH   120
#define WW   160
#define NH_  8
#define HD   20
#define HDP  32            // head dim padded to 32 (zeros) for K=32 MFMA
#define NN   3840          // sequence length (C*H)
#define ROWS 3840
#define NBH  32            // B * NH
#define LOG2E 1.44269504088896f

typedef float f32x4 __attribute__((ext_vector_type(4)));
typedef short s16x8 __attribute__((ext_vector_type(8)));
typedef short s16x4 __attribute__((ext_vector_type(4)));

static __device__ __forceinline__ unsigned short f2bf(float x) {
    return __builtin_bit_cast(unsigned short, __float2bfloat16(x));
}
static __device__ __forceinline__ float bf2f(unsigned short u) {
    unsigned v = ((unsigned)u) << 16;
    return __builtin_bit_cast(float, v);
}
static __device__ __forceinline__ float exp2fast(float x) {
#if defined(__has_builtin) && __has_builtin(__builtin_amdgcn_exp2f)
    return __builtin_amdgcn_exp2f(x);
#else
    float r; asm("v_exp_f32 %0, %1" : "=v"(r) : "v"(x)); return r;
#endif
}

// exp2 four lanes then pack to bf16 by TRUNCATION (validated R18/R19:
// absmax 0.0176 < 0.0306). BUILTIN-ONLY pack — perm path validated
// R5/R9-R19. Do NOT use the cvt_pk inline-asm variant (R7/R8 corruption).
static __device__ __forceinline__ s16x4 exp4_pack(f32x4 e) {
    unsigned u0 = __builtin_bit_cast(unsigned, exp2fast(e[0]));
    unsigned u1 = __builtin_bit_cast(unsigned, exp2fast(e[1]));
    unsigned u2 = __builtin_bit_cast(unsigned, exp2fast(e[2]));
    unsigned u3 = __builtin_bit_cast(unsigned, exp2fast(e[3]));
    uint2 w;
#if defined(__has_builtin) && __has_builtin(__builtin_amdgcn_perm)
    w.x = __builtin_amdgcn_perm(u1, u0, 0x07060302u);
    w.y = __builtin_amdgcn_perm(u3, u2, 0x07060302u);
#else
    w.x = (u0 >> 16) | (u1 & 0xffff0000u);
    w.y = (u2 >> 16) | (u3 & 0xffff0000u);
#endif
    return __builtin_bit_cast(s16x4, w);
}

static __device__ __forceinline__ f32x4 mfma32(s16x8 a, s16x8 b, f32x4 c) {
    return __builtin_amdgcn_mfma_f32_16x16x32_bf16(a, b, c, 0, 0, 0);
}
// concat two s16x4 into a K=32 fragment half-pair (register pairing, no ops)
static __device__ __forceinline__ s16x8 cat44(s16x4 a, s16x4 b) {
    s16x8 r;
    r[0]=a[0]; r[1]=a[1]; r[2]=a[2]; r[3]=a[3];
    r[4]=b[0]; r[5]=b[1]; r[6]=b[2]; r[7]=b[3];
    return r;
}

// ---------------- W prep: f32 -> bf16 [o][k]; Wq pre-scaled by log2(e) ----
__global__ __launch_bounds__(256)
void wprep_kernel(const float* __restrict__ Wq, const float* __restrict__ Wk,
                  const float* __restrict__ Wv,
                  unsigned short* __restrict__ wqb, unsigned short* __restrict__ wkb,
                  unsigned short* __restrict__ wvb)
{
    int i = blockIdx.x*256 + threadIdx.x;
    if (i < WW*WW) {
        wqb[i] = f2bf(Wq[i] * LOG2E);
        wkb[i] = f2bf(Wk[i]);
        wvb[i] = f2bf(Wv[i]);
    }
}

// ---------------- Projection via MFMA (no LDS), R18 regrid ---------------
__global__ __launch_bounds__(256)
void proj_mfma_kernel(const float* __restrict__ x,
                      const unsigned short* __restrict__ wqb,
                      const unsigned short* __restrict__ wkb,
                      const unsigned short* __restrict__ wvb,
                      const float* __restrict__ bq, const float* __restrict__ bk,
                      const float* __restrict__ bv,
                      unsigned short* __restrict__ qt, unsigned short* __restrict__ kt,
                      unsigned short* __restrict__ vb)
{
    const int tid  = threadIdx.x;
    const int wv   = tid >> 6;
    const int lane = tid & 63;
    const int g = lane >> 4, c = lane & 15;
    const int r0 = blockIdx.x*32 + (wv & 1)*16;   // wave's 16-row tile
    const int ch = wv >> 1;                        // col half: tiles ch*5..ch*5+4

    s16x8 A[5];
    const float* xrow = x + (size_t)(r0 + c)*WW;
    #pragma unroll
    for (int s = 0; s < 5; ++s) {
        float4 v0 = *(const float4*)(xrow + s*32 + g*8);
        float4 v1 = *(const float4*)(xrow + s*32 + g*8 + 4);
        s16x8 a;
        a[0]=(short)f2bf(v0.x); a[1]=(short)f2bf(v0.y);
        a[2]=(short)f2bf(v0.z); a[3]=(short)f2bf(v0.w);
        a[4]=(short)f2bf(v1.x); a[5]=(short)f2bf(v1.y);
        a[6]=(short)f2bf(v1.z); a[7]=(short)f2bf(v1.w);
        A[s] = a;
    }

    size_t baseqk[4], basev[4];
    #pragma unroll
    for (int rr = 0; rr < 4; ++rr) {
        int R  = r0 + g*4 + rr;
        int b  = R / ROWS;
        int r  = R % ROWS;
        int nh = r / 480;
        int rm = r % 480;
        int d  = rm / 24;
        int n1 = rm % 24;
        int bh = b*NH_ + nh;
        baseqk[rr] = ((size_t)bh*NN + n1*160)*HDP + d;
        basev[rr]  = ((size_t)bh*HD + d)*NN + n1*160;
    }

    const f32x4 zero4 = {0.f, 0.f, 0.f, 0.f};
    for (int nt = ch*5; nt < ch*5 + 5; ++nt) {
        const size_t wbase = (size_t)(nt*16 + c)*WW;
        f32x4 aq = zero4, ak = zero4, av = zero4;
        #pragma unroll
        for (int s = 0; s < 5; ++s) {
            s16x8 Bq = *(const s16x8*)(wqb + wbase + s*32 + g*8);
            aq = mfma32(A[s], Bq, aq);
            s16x8 Bk = *(const s16x8*)(wkb + wbase + s*32 + g*8);
            ak = mfma32(A[s], Bk, ak);
            s16x8 Bv = *(const s16x8*)(wvb + wbase + s*32 + g*8);
            av = mfma32(A[s], Bv, av);
        }
        const int o = nt*16 + c;
        const float bqv = bq[o]*LOG2E, bkv = bk[o], bvv = bv[o];
        #pragma unroll
        for (int rr = 0; rr < 4; ++rr) {
            qt[baseqk[rr] + (size_t)o*HDP] = f2bf(aq[rr] + bqv);
            kt[baseqk[rr] + (size_t)o*HDP] = f2bf(ak[rr] + bkv);
            vb[basev[rr] + o]              = f2bf(av[rr] + bvv);
        }
    }
}

// ---------------- Pass 1 (fused): Z + quad-major Vz (R19-exact, passing) -
__global__ __launch_bounds__(256, 4)
void zinv_kernel(const unsigned short* __restrict__ qt,
                 const unsigned short* __restrict__ kt,
                 const unsigned short* __restrict__ vb,
                 unsigned short* __restrict__ vzt)
{
    __shared__ float zred[4][64];
    const int blk  = ((int)blockIdx.x & 7) * (NBH*(NN/64)/8) + ((int)blockIdx.x >> 3);
    const int bh   = blk / (NN/64);
    const int m0   = (blk % (NN/64)) * 64;
    const int tid  = threadIdx.x;
    const int wv   = tid >> 6;
    const int lane = tid & 63;
    const int g = lane >> 4, c = lane & 15;

    s16x8 qa[4];
    #pragma unroll
    for (int ms = 0; ms < 4; ++ms)
        qa[ms] = *(const s16x8*)(qt + ((size_t)bh*NN + m0 + ms*16 + c)*HDP + g*8);

    const f32x4 zero4 = {0.f, 0.f, 0.f, 0.f};
    f32x4 z[4];
    #pragma unroll
    for (int ms = 0; ms < 4; ++ms) z[ms] = zero4;

    const unsigned short* kbase = kt + (size_t)bh*NN*HDP;
    const int nbeg = wv * (NN/4);
    const int nend = nbeg + NN/4;

    s16x8 kb0 = *(const s16x8*)(kbase + (size_t)(nbeg +      c)*HDP + g*8);
    s16x8 kb1 = *(const s16x8*)(kbase + (size_t)(nbeg + 16 + c)*HDP + g*8);

    for (int n = nbeg; n < nend - 32; n += 32) {
        s16x8 nk0 = *(const s16x8*)(kbase + (size_t)(n + 32 +      c)*HDP + g*8);
        s16x8 nk1 = *(const s16x8*)(kbase + (size_t)(n + 48 +      c)*HDP + g*8);
        #pragma unroll
        for (int ms = 0; ms < 4; ++ms) {
            f32x4 e0 = mfma32(qa[ms], kb0, zero4);
            f32x4 e1 = mfma32(qa[ms], kb1, zero4);
            #pragma unroll
            for (int rr = 0; rr < 4; ++rr)
                z[ms][rr] += exp2fast(e0[rr]) + exp2fast(e1[rr]);
        }
        kb0 = nk0; kb1 = nk1;
    }
    #pragma unroll
    for (int ms = 0; ms < 4; ++ms) {
        f32x4 e0 = mfma32(qa[ms], kb0, zero4);
        f32x4 e1 = mfma32(qa[ms], kb1, zero4);
        #pragma unroll
        for (int rr = 0; rr < 4; ++rr)
            z[ms][rr] += exp2fast(e0[rr]) + exp2fast(e1[rr]);
    }

    #pragma unroll
    for (int ms = 0; ms < 4; ++ms) {
        #pragma unroll
        for (int rr = 0; rr < 4; ++rr) {
            float v = z[ms][rr];
            v += __shfl_xor(v, 1);
            v += __shfl_xor(v, 2);
            v += __shfl_xor(v, 4);
            v += __shfl_xor(v, 8);
            if (c == 0) zred[wv][ms*16 + g*4 + rr] = v;
        }
    }
    __syncthreads();
    if (tid < 64) {
        float s = zred[0][tid] + zred[1][tid] + zred[2][tid] + zred[3][tid];
        zred[0][tid] = 1.0f / s;      // same-thread RMW of own slot: safe
    }
    __syncthreads();

    // fused Vz: thread = (dp = tid&31, half = tid>>5); m-sub = half*8
    {
        const int dp   = tid & 31;
        const int half = tid >> 5;
        const int mloc = half * 8;
        unsigned short pv[8];
        if (dp < HD) {
            const unsigned short* src = vb + ((size_t)bh*HD + dp)*NN + m0 + mloc;
            s16x8 raw = *(const s16x8*)src;    // 16B contiguous, aligned
            #pragma unroll
            for (int j = 0; j < 8; ++j)
                pv[j] = f2bf(bf2f((unsigned short)raw[j]) * zred[0][mloc + j]);
        } else {
            #pragma unroll
            for (int j = 0; j < 8; ++j) pv[j] = 0;
        }
        unsigned short* dst = vzt + (size_t)bh*HDP*NN
                                  + (size_t)(m0/4 + half*2)*(HDP*4) + dp*4;
        s16x4 o0, o1;
        o0[0]=(short)pv[0]; o0[1]=(short)pv[1]; o0[2]=(short)pv[2]; o0[3]=(short)pv[3];
        o1[0]=(short)pv[4]; o1[1]=(short)pv[5]; o1[2]=(short)pv[6]; o1[3]=(short)pv[7];
        *(s16x4*)dst = o0;
        *(s16x4*)(dst + HDP*4) = o1;
    }
}

// ---------------- Pass 2: out = Vz * exp2(Q^T K) ------------------------
// R20: setprio REVERTED (R19 regression); ping-pong 2x-unrolled m-loop —
// named frag sets A/B alternate compute/prefetch, eliminating the ~24
// rotation v_movs per step. 15 steps = 7 double-iters + epilogue step (A).
__global__ __launch_bounds__(256, 3)
void attn_out_kernel(const unsigned short* __restrict__ qt,
                     const unsigned short* __restrict__ kt,
                     const unsigned short* __restrict__ vzt,
                     float* __restrict__ y)
{
    __shared__ float red[3][32][64];   // 24 KB
    const int blk  = ((int)blockIdx.x & 7) * (NBH*(NN/64)/8) + ((int)blockIdx.x >> 3);
    const int bh   = blk / (NN/64);
    const int n0   = (blk % (NN/64)) * 64;
    const int tid  = threadIdx.x;
    const int wv   = tid >> 6;
    const int lane = tid & 63;
    const int g = lane >> 4, c = lane & 15;
    const int b = bh >> 3, nh = bh & 7;

    const f32x4 zero4 = {0.f, 0.f, 0.f, 0.f};
    const unsigned short* qb  = qt  + (size_t)bh*NN*HDP;
    const unsigned short* kbp = kt  + (size_t)bh*NN*HDP;
    const unsigned short* vp  = vzt + (size_t)bh*HDP*NN;

    s16x8 kb[4];
    #pragma unroll
    for (int ns = 0; ns < 4; ++ns)
        kb[ns] = *(const s16x8*)(kbp + ((size_t)(n0 + ns*16 + c))*HDP + g*8);

    f32x4 acc[2][4];
    #pragma unroll
    for (int ds = 0; ds < 2; ++ds)
        #pragma unroll
        for (int ns = 0; ns < 4; ++ns) acc[ds][ns] = zero4;

    const int mbeg = wv * (NN/4);          // 960 m per wave = 15 steps of 64

    #define LOAD_FRAGS(QA, VA, MM)                                            \
        _Pragma("unroll")                                                     \
        for (int j = 0; j < 4; ++j)                                           \
            QA[j] = *(const s16x8*)(qb + ((size_t)((MM) + j*16 + c))*HDP + g*8); \
        _Pragma("unroll")                                                     \
        for (int ds = 0; ds < 2; ++ds)                                        \
            _Pragma("unroll")                                                 \
            for (int j = 0; j < 4; ++j)                                       \
                VA[ds][j] = *(const s16x4*)(vp + (size_t)(((MM) >> 2) + j*4 + g)*(HDP*4) \
                                               + (ds*16 + c)*4);

    #define COMPUTE_STEP(QA, VA)                                              \
        _Pragma("unroll")                                                     \
        for (int ns = 0; ns < 4; ++ns) {                                      \
            f32x4 e0 = mfma32(QA[0], kb[ns], zero4);                          \
            f32x4 e1 = mfma32(QA[1], kb[ns], zero4);                          \
            f32x4 e2 = mfma32(QA[2], kb[ns], zero4);                          \
            f32x4 e3 = mfma32(QA[3], kb[ns], zero4);                          \
            s16x8 P01 = cat44(exp4_pack(e0), exp4_pack(e1));                  \
            s16x8 P23 = cat44(exp4_pack(e2), exp4_pack(e3));                  \
            acc[0][ns] = mfma32(cat44(VA[0][0], VA[0][1]), P01, acc[0][ns]);  \
            acc[0][ns] = mfma32(cat44(VA[0][2], VA[0][3]), P23, acc[0][ns]);  \
            acc[1][ns] = mfma32(cat44(VA[1][0], VA[1][1]), P01, acc[1][ns]);  \
            acc[1][ns] = mfma32(cat44(VA[1][2], VA[1][3]), P23, acc[1][ns]);  \
        }

    s16x8 qaA[4], qaB[4];
    s16x4 vaA[2][4], vaB[2][4];
    LOAD_FRAGS(qaA, vaA, mbeg)                       // step 0

    for (int k = 0; k < 14; k += 2) {
        const int mB = mbeg + (k+1)*64;
        const int mA = mbeg + (k+2)*64;
        LOAD_FRAGS(qaB, vaB, mB)                     // prefetch step k+1
        COMPUTE_STEP(qaA, vaA)                       // compute step k
        LOAD_FRAGS(qaA, vaA, mA)                     // prefetch step k+2
        COMPUTE_STEP(qaB, vaB)                       // compute step k+1
    }
    COMPUTE_STEP(qaA, vaA)                           // epilogue: step 14

    #undef LOAD_FRAGS
    #undef COMPUTE_STEP

    float* af = (float*)acc;   // 32 contiguous f32
    if (wv > 0) {
        #pragma unroll
        for (int j = 0; j < 32; ++j) red[wv-1][j][lane] = af[j];
    }
    __syncthreads();
    if (wv == 0) {
        #pragma unroll
        for (int j = 0; j < 32; ++j)
            af[j] += red[0][j][lane] + red[1][j][lane] + red[2][j][lane];
        float* yb = y + (size_t)b * CC * HH * WW;
        #pragma unroll
        for (int ds = 0; ds < 2; ++ds) {
            #pragma unroll
            for (int ns = 0; ns < 4; ++ns) {
                #pragma unroll
                for (int rr = 0; rr < 4; ++rr) {
                    int dd = ds*16 + g*4 + rr;
                    if (dd < HD)
                        yb[((size_t)(dd*NH_ + nh))*NN + n0 + ns*16 + c] = acc[ds][ns][rr];
                }
            }
        }
    }
}

extern "C" void kernel_launch(void* const* d_in, const int* in_sizes, int n_in,
                              void* d_out, int out_size, void* d_ws, size_t ws_size,
                              hipStream_t stream)
{
    const float* x  = (const float*)d_in[0];
    const float* Wq = (const float*)d_in[1];
    const float* bq = (const float*)d_in[2];
    const float* Wk = (const float*)d_in[3];
    const float* bk = (const float*)d_in[4];
    const float* Wv = (const float*)d_in[5];
    const float* bv = (const float*)d_in[6];
    float* y = (float*)d_out;

    const size_t QT_E = (size_t)NBH * NN * HDP;      // 3,932,160 bf16
    unsigned short* qt  = (unsigned short*)d_ws;
    unsigned short* kt  = qt + QT_E;
    unsigned short* vb  = kt + QT_E;
    unsigned short* vzt = vb + (size_t)NBH * HD * NN;
    unsigned short* wqb = vzt + QT_E;
    unsigned short* wkb = wqb + WW*WW;
    unsigned short* wvb = wkb + WW*WW;               // total ~28.7 MB

    hipMemsetAsync(qt, 0, 2 * QT_E * sizeof(unsigned short), stream);

    wprep_kernel<<<dim3((WW*WW + 255)/256), dim3(256), 0, stream>>>(
        Wq, Wk, Wv, wqb, wkb, wvb);
    proj_mfma_kernel<<<dim3(BB*ROWS/32), dim3(256), 0, stream>>>(
        x, wqb, wkb, wvb, bq, bk, bv, qt, kt, vb);
    zinv_kernel<<<dim3(NBH*(NN/64)), dim3(256), 0, stream>>>(qt, kt, vb, vzt);
    attn_out_kernel<<<dim3(NBH*(NN/64)), dim3(256), 0, stream>>>(qt, kt, vzt, y);
}